// Round 3
// baseline (493.237 us; speedup 1.0000x reference)
//
#include <hip/hip_runtime.h>

#define C_DIM 768

// d_ws layout:
//   [0)       8 x uint counts
//   [1024)    WaT4: granule (k4, o) -> float4 {Wa[o][4k4..4k4+3]}, g = k4*192 + o
//             o in [0,168): Wa rows (a*56+e*8+r); o in [168,175): w_gate col e; else 0
//   [590848)  WbT4: granule (o, c4) -> float4 {WbT[o][4c4..+3]}, g = o*192 + c4, o = a*56+k

__global__ __launch_bounds__(256) void transpose_w(
    const float* __restrict__ wa, const float* __restrict__ wg,
    const float* __restrict__ wb,
    float4* __restrict__ waT4, float4* __restrict__ wbT4) {
  const int b = blockIdx.x;
  if (b < 144) {
    const int g = b * 256 + threadIdx.x;   // 192*192 = 36864
    const int o = g % 192, k4 = g / 192;
    float4 v = make_float4(0.f, 0.f, 0.f, 0.f);
    if (o < 168) {
      v = *(const float4*)(wa + (size_t)o * C_DIM + k4 * 4);
    } else if (o < 175) {
      const int e = o - 168;
      v.x = wg[(k4 * 4 + 0) * 7 + e];
      v.y = wg[(k4 * 4 + 1) * 7 + e];
      v.z = wg[(k4 * 4 + 2) * 7 + e];
      v.w = wg[(k4 * 4 + 3) * 7 + e];
    }
    waT4[g] = v;
  } else {
    const int g = (b - 144) * 256 + threadIdx.x;   // 168*192 = 32256 exactly
    const int c4 = g % 192, ak = g / 192;
    const int a = ak / 56, k = ak - a * 56;
    const int e = k >> 3, r = k & 7;
    const float* s = wb + ((size_t)(a * 7 + e) * C_DIM + c4 * 4) * 8 + r;
    wbT4[g] = make_float4(s[0], s[8], s[16], s[24]);
  }
}

// 16 tokens per block (4 per wave): grid = T/16 = 1024 blocks.
// VGPR budget: __launch_bounds__(256,2) caps at 256 so the allocator is NOT
// forced into the 128-cap AGPR/scratch split seen at (256,4) [VGPR_Count=64,
// +52MB scratch writes]. Natural allocation (~100, cf. round-0's 108 with a
// strictly larger live set) lands <=128 -> hardware fits 4 waves/SIMD:
// 4 blocks/CU (LDS 22KB x 4 = 88KB <= 160KB), grid supplies 4096 waves.
__global__ __launch_bounds__(256, 2) void moe_main(
    const float* __restrict__ x, const float4* __restrict__ waT4,
    const float4* __restrict__ wbT4, float* __restrict__ out,
    unsigned int* __restrict__ counts, int T) {
  __shared__ float xs[4][2][4][64];   // per-wave double-buffered x chunk (8 KB)
  __shared__ float hsT[168][20];      // h^T [o][tok], stride 20 (16B-aligned cols)

  const int tid = threadIdx.x;
  const int w = tid >> 6, lane = tid & 63;
  const int half = lane >> 5, l5 = lane & 31;
  const int t0 = blockIdx.x * 16;
  const int tb = w * 4;

  // ---------------- Stage 1: h = x @ WaT (+ gating logits) ----------------
  // lane-half token split: half h owns tokens [h*2, h*2+2); lane covers
  // o = l5 + 32m, m=0..5 (o in 0..191; rows >=175 are zero-padded).
  float acc1[2][6];
  #pragma unroll
  for (int tl = 0; tl < 2; ++tl)
    #pragma unroll
    for (int m = 0; m < 6; ++m) acc1[tl][m] = 0.f;

  const int xt = lane >> 4, xc = (lane & 15) * 4;
  const float* xbase = x + (size_t)(t0 + tb + xt) * C_DIM + xc;
  const float4* wa_l = waT4 + l5;

  // warmup: chunk 0 staged, chunk 1 in regs, weight steps 0,1 in flight
  float4 xr = *(const float4*)(xbase);
  *(float4*)&xs[w][0][xt][xc] = xr;
  xr = *(const float4*)(xbase + 64);

  float4 wv[2][6];
  #pragma unroll
  for (int m = 0; m < 6; ++m) wv[0][m] = wa_l[32 * m];
  #pragma unroll
  for (int m = 0; m < 6; ++m) wv[1][m] = wa_l[192 + 32 * m];

  #pragma unroll 1
  for (int ch = 0; ch < 12; ++ch) {
    // hand next chunk to LDS, issue load for chunk+2
    if (ch < 11) {
      *(float4*)&xs[w][(ch + 1) & 1][xt][xc] = xr;
      if (ch < 10) {
        xr = *(const float4*)(xbase + (ch + 2) * 64);
      }
    }
    const int buf = ch & 1;
    #pragma unroll
    for (int kk = 0; kk < 16; ++kk) {
      const int p = kk & 1;   // (ch*16+kk)&1 == kk&1 since 16 is even
      float4 xv[2];
      #pragma unroll
      for (int tl = 0; tl < 2; ++tl)
        xv[tl] = *(const float4*)&xs[w][buf][half * 2 + tl][kk * 4];
      #pragma unroll
      for (int m = 0; m < 6; ++m) {
        const float4 wvv = wv[p][m];
        #pragma unroll
        for (int tl = 0; tl < 2; ++tl) {
          float s = acc1[tl][m];
          s = fmaf(xv[tl].x, wvv.x, s);
          s = fmaf(xv[tl].y, wvv.y, s);
          s = fmaf(xv[tl].z, wvv.z, s);
          s = fmaf(xv[tl].w, wvv.w, s);
          acc1[tl][m] = s;
        }
      }
      // prefetch weights for step+2 into the buffer just consumed (clamped tail)
      int gn = ch * 16 + kk + 2;
      gn = gn > 191 ? 191 : gn;
      #pragma unroll
      for (int m = 0; m < 6; ++m) wv[p][m] = wa_l[(size_t)gn * 192 + 32 * m];
    }
  }

  // ---- argmax over logits (o=168+e -> m=5, l5=8+e, same half), counts ----
  int be[2];
  #pragma unroll
  for (int tl = 0; tl < 2; ++tl) {
    float best = __shfl(acc1[tl][5], (lane & 32) + 8);
    int b = 0;
    #pragma unroll
    for (int e = 1; e < 7; ++e) {
      const float lv = __shfl(acc1[tl][5], (lane & 32) + 8 + e);
      if (lv > best) { best = lv; b = e; }   // strict > = lowest-index tie-break
    }
    be[tl] = b;
  }
  if (l5 == 0) {
    #pragma unroll
    for (int tl = 0; tl < 2; ++tl) atomicAdd(&counts[be[tl]], 1u);
  }

  // ---- scale by hierarchy coefficient, write h^T (same-wave consumer) ----
  #pragma unroll
  for (int tl = 0; tl < 2; ++tl) {
    const int b = be[tl];
    const int tcol = tb + half * 2 + tl;
    #pragma unroll
    for (int m = 0; m < 6; ++m) {
      const int o = l5 + 32 * m;
      if (o < 168) {
        const int e = (o % 56) >> 3;
        float co = (e == b) ? 1.f : 0.f;
        if (b >= 4 && e < 4) co += 0.25f;
        if (b == 6 && (e == 4 || e == 5)) co += 0.5f;
        hsT[o][tcol] = acc1[tl][m] * co;
      }
    }
  }
  // no __syncthreads: each wave reads only its own hsT columns below

  // ---------------- Stage 2: y[a] = h[a] @ WbT[a] ----------------
  const float4* wb_l = wbT4 + lane;
  float4 u[2][3], hb[2];
  #pragma unroll
  for (int cc = 0; cc < 3; ++cc) {
    u[0][cc] = wb_l[64 * cc];
    u[1][cc] = wb_l[192 + 64 * cc];
  }
  hb[0] = *(const float4*)&hsT[0][tb];
  hb[1] = *(const float4*)&hsT[1][tb];

  #pragma unroll 1
  for (int a = 0; a < 3; ++a) {
    float4 acc2[3][4];
    #pragma unroll
    for (int cc = 0; cc < 3; ++cc)
      #pragma unroll
      for (int t = 0; t < 4; ++t) acc2[cc][t] = make_float4(0.f, 0.f, 0.f, 0.f);

    #pragma unroll 4
    for (int kq = 0; kq < 56; ++kq) {
      const int o = a * 56 + kq;
      const int p = kq & 1;   // (a*56+kq)&1 == kq&1 since 56 is even
      const float hv[4] = {hb[p].x, hb[p].y, hb[p].z, hb[p].w};
      const float4 w0 = u[p][0], w1 = u[p][1], w2 = u[p][2];
      #pragma unroll
      for (int t = 0; t < 4; ++t) {
        const float s = hv[t];
        acc2[0][t].x = fmaf(w0.x, s, acc2[0][t].x);
        acc2[0][t].y = fmaf(w0.y, s, acc2[0][t].y);
        acc2[0][t].z = fmaf(w0.z, s, acc2[0][t].z);
        acc2[0][t].w = fmaf(w0.w, s, acc2[0][t].w);
        acc2[1][t].x = fmaf(w1.x, s, acc2[1][t].x);
        acc2[1][t].y = fmaf(w1.y, s, acc2[1][t].y);
        acc2[1][t].z = fmaf(w1.z, s, acc2[1][t].z);
        acc2[1][t].w = fmaf(w1.w, s, acc2[1][t].w);
        acc2[2][t].x = fmaf(w2.x, s, acc2[2][t].x);
        acc2[2][t].y = fmaf(w2.y, s, acc2[2][t].y);
        acc2[2][t].z = fmaf(w2.z, s, acc2[2][t].z);
        acc2[2][t].w = fmaf(w2.w, s, acc2[2][t].w);
      }
      // prefetch o+2 into just-consumed buffers (clamped tail; row 167 re-read)
      int on = o + 2;
      on = on > 167 ? 167 : on;
      #pragma unroll
      for (int cc = 0; cc < 3; ++cc) u[p][cc] = wb_l[(size_t)on * 192 + 64 * cc];
      hb[p] = *(const float4*)&hsT[on][tb];
    }

    #pragma unroll
    for (int cc = 0; cc < 3; ++cc)
      #pragma unroll
      for (int t = 0; t < 4; ++t)
        *(float4*)(out + ((size_t)a * T + t0 + tb + t) * C_DIM + cc * 256 + lane * 4)
            = acc2[cc][t];
  }
}

// loss = 2 * cv2(counts)  (importance == load == counts when K=1, gate==1.0)
__global__ void loss_k(const unsigned int* __restrict__ counts,
                       float* __restrict__ out, int T) {
  if (threadIdx.x == 0) {
    float c[7], mean = 0.f;
    #pragma unroll
    for (int e = 0; e < 7; ++e) { c[e] = (float)counts[e]; mean += c[e]; }
    mean *= (1.f / 7.f);
    float var = 0.f;
    #pragma unroll
    for (int e = 0; e < 7; ++e) { const float d = c[e] - mean; var += d * d; }
    var *= (1.f / 6.f);  // ddof=1
    out[(size_t)3 * T * C_DIM] = 2.f * (var / (mean * mean + 1e-10f));
  }
}

extern "C" void kernel_launch(void* const* d_in, const int* in_sizes, int n_in,
                              void* d_out, int out_size, void* d_ws, size_t ws_size,
                              hipStream_t stream) {
  const float* x  = (const float*)d_in[0];
  const float* wg = (const float*)d_in[1];
  const float* Wa = (const float*)d_in[2];
  const float* Wb = (const float*)d_in[3];
  float* out = (float*)d_out;

  unsigned int* counts = (unsigned int*)d_ws;
  float4* waT4 = (float4*)((char*)d_ws + 1024);
  float4* wbT4 = (float4*)((char*)d_ws + 590848);

  const int T = in_sizes[0] / C_DIM;  // 16384

  hipMemsetAsync(counts, 0, 8 * sizeof(unsigned int), stream);
  transpose_w<<<dim3(270), dim3(256), 0, stream>>>(Wa, wg, Wb, waT4, wbT4);
  moe_main<<<dim3(T / 16), dim3(256), 0, stream>>>(x, waT4, wbT4, out, counts, T);
  loss_k<<<dim3(1), dim3(64), 0, stream>>>(counts, out, T);
}